// Round 10
// baseline (796.809 us; speedup 1.0000x reference)
//
#include <hip/hip_runtime.h>
#include <hip/hip_cooperative_groups.h>

namespace cg = cooperative_groups;

// GNN TARnet: h = x*emb -> 2x graph conv -> two prob heads.
// R13: maximal dispatch fusion via cooperative launch. R12 left ~240us of
//     wall time unattributable to kernels (~25-30us/dispatch launch-path
//     cost, or mis-estimated invisible kernels). Decisive test: collapse
//     {memset,count,scan,fill} -> k_csr (cooperative, 1 dispatch) and
//     {reduce,final} -> k_redfin (cooperative, 1 dispatch). 9 -> 6
//     dispatches. k_prepare/k_conv/k_head bodies byte-identical to R12.

constexpr int B = 8, N = 5000, E = 160000, D = 64, H = 128;
constexpr int BN = B * N;           // 40000
constexpr int ND = N * D;           // 320000
constexpr long BND = (long)BN * D;  // 2,560,000
constexpr int KC = 320;             // k-chunk per head block
constexpr int NIT = KC / 8;         // 40 k-iters per thread
constexpr int XB = ND / KC;         // 1000 x-blocks per head

using f32x4 = __attribute__((ext_vector_type(4))) float;

__device__ __forceinline__ float elu_f(float x) {
    return x > 0.0f ? x : __expf(x) - 1.0f;
}

__device__ __forceinline__ void g2lds16(const float* g, float* l) {
    __builtin_amdgcn_global_load_lds(
        (const __attribute__((address_space(1))) void*)g,
        (__attribute__((address_space(3))) void*)l, 16, 0, 0);
}

// ---------------- cooperative CSR build: zero + count + scan + fill ----------
// cnt and cursor are CONTIGUOUS in workspace (cursor = cnt + N).
__global__ __launch_bounds__(256) void k_csr(const int* __restrict__ edges,
                                             int* __restrict__ cnt,
                                             int* __restrict__ cursor,
                                             int* __restrict__ offs,
                                             int* __restrict__ elist) {
    cg::grid_group grid = cg::this_grid();
    int t = threadIdx.x;
    int gtid = blockIdx.x * 256 + t;
    int GT = gridDim.x * 256;

    // phase 0: zero cnt + cursor (contiguous 2N ints)
    for (int i = gtid; i < 2 * N; i += GT) cnt[i] = 0;
    grid.sync();

    // phase 1: count
    for (int i = gtid; i < E; i += GT) atomicAdd(&cnt[edges[2 * i + 1]], 1);
    grid.sync();

    // phase 2: exclusive scan (block 0 only; 256 threads x CH=20)
    if (blockIdx.x == 0) {
        __shared__ int part[256];
        const int CH = 20;
        int base = t * CH;
        int s = 0;
        for (int i = 0; i < CH; ++i) { int idx = base + i; if (idx < N) s += cnt[idx]; }
        part[t] = s;
        __syncthreads();
        for (int off = 1; off < 256; off <<= 1) {
            int add = (t >= off) ? part[t - off] : 0;
            __syncthreads();
            part[t] += add;
            __syncthreads();
        }
        int run = part[t] - s;
        for (int i = 0; i < CH; ++i) {
            int idx = base + i;
            if (idx < N) { offs[idx] = run; run += cnt[idx]; }
        }
        if (t == 255) offs[N] = run;
    }
    grid.sync();

    // phase 3: fill
    for (int i = gtid; i < E; i += GT) {
        int child = edges[2 * i + 1];
        int pos = offs[child] + atomicAdd(&cursor[child], 1);
        elist[pos] = edges[2 * i];
    }
}

// ---------------- prepare (conv1): M = elu(elu((x*emb) @ W1) @ W2) ----------
// M written node-major M[(n*8+b)*64+c].
__global__ __launch_bounds__(512) void k_prepare(const float* __restrict__ xsrc,
                                                 const float* __restrict__ emb,
                                                 const float* __restrict__ W1,
                                                 const float* __restrict__ W2,
                                                 float* __restrict__ M) {
    __shared__ float sW1[64 * 64];      // 16 KB
    __shared__ float sP[128 * 65];      // 33.3 KB
    int t = threadIdx.x;
    int r0 = blockIdx.x * 128;
    for (int i = t; i < 4096; i += 512) sW1[i] = W1[i];
    for (int i = t; i < 128 * 64; i += 512) {
        int r = i >> 6, c = i & 63;
        int row = r0 + r;
        float v = 0.0f;
        if (row < BN) {
            int n = row % N;
            v = xsrc[row] * emb[n * 64 + c];
        }
        sP[r * 65 + c] = v;
    }
    __syncthreads();

    int cg_ = t & 15, rg = t >> 4;
    float acc[4][4] = {};
    #pragma unroll 4
    for (int k = 0; k < 64; ++k) {
        float a[4];
        #pragma unroll
        for (int i = 0; i < 4; ++i) a[i] = sP[(rg * 4 + i) * 65 + k];
        float4 bb = *reinterpret_cast<const float4*>(&sW1[k * 64 + cg_ * 4]);
        #pragma unroll
        for (int i = 0; i < 4; ++i) {
            acc[i][0] += a[i] * bb.x; acc[i][1] += a[i] * bb.y;
            acc[i][2] += a[i] * bb.z; acc[i][3] += a[i] * bb.w;
        }
    }
    __syncthreads();
    #pragma unroll
    for (int i = 0; i < 4; ++i)
        #pragma unroll
        for (int j = 0; j < 4; ++j)
            sP[(rg * 4 + i) * 65 + cg_ * 4 + j] = elu_f(acc[i][j]);
    __syncthreads();

    float acc2[4][4] = {};
    #pragma unroll 4
    for (int k = 0; k < 64; ++k) {
        float a[4];
        #pragma unroll
        for (int i = 0; i < 4; ++i) a[i] = sP[(rg * 4 + i) * 65 + k];
        float4 bb = *reinterpret_cast<const float4*>(&W2[k * 64 + cg_ * 4]);
        #pragma unroll
        for (int i = 0; i < 4; ++i) {
            acc2[i][0] += a[i] * bb.x; acc2[i][1] += a[i] * bb.y;
            acc2[i][2] += a[i] * bb.z; acc2[i][3] += a[i] * bb.w;
        }
    }
    #pragma unroll
    for (int i = 0; i < 4; ++i) {
        int row = r0 + rg * 4 + i;
        if (row < BN) {
            int b = row / N;
            int n = row - b * N;
            float4 o = make_float4(elu_f(acc2[i][0]), elu_f(acc2[i][1]),
                                   elu_f(acc2[i][2]), elu_f(acc2[i][3]));
            *reinterpret_cast<float4*>(&M[((long)n * 8 + b) * 64 + cg_ * 4]) = o;
        }
    }
}

// ---------------- fused conv: gather + update FFN (+ optional next-prepare) ----
// M node-major [N][8][64]; block = 8 nodes x 8 batches. PREP=1: h inline from
// x,emb; also runs conv2 prepare tail. Byte-identical to R12.
template <int PREP>
__global__ __launch_bounds__(512, 8) void k_conv(const float* __restrict__ h,
                                                 const float* __restrict__ xsrc,
                                                 const float* __restrict__ emb,
                                                 const float* __restrict__ M,
                                                 const int* __restrict__ offs,
                                                 const int* __restrict__ elist,
                                                 const float* __restrict__ W1u,  // [128][64]
                                                 const float* __restrict__ b1u,
                                                 const float* __restrict__ W2u,  // [64][64]
                                                 const float* __restrict__ b2u,
                                                 float* __restrict__ hout,
                                                 const float* __restrict__ W1p,  // [64][64]
                                                 const float* __restrict__ W2p,  // [64][64]
                                                 float* __restrict__ Mout) {
    __shared__ float sP[64 * 129];      // 33 KB; rows lr = n_local*8 + b
    int t = threadIdx.x;
    int n0 = blockIdx.x * 8;

    // A1: stage h rows -> sP cols [0,64): 1024 float4, 2 per thread
    #pragma unroll
    for (int q = 0; q < 2; ++q) {
        int s = t + q * 512;
        int lr = s >> 4, c4 = s & 15;
        int nl = lr >> 3, b = lr & 7;
        long grow = (long)b * N + (n0 + nl);
        float4 v;
        if (PREP) {
            float xv = xsrc[grow];
            float4 ev = *reinterpret_cast<const float4*>(
                &emb[(long)(n0 + nl) * 64 + c4 * 4]);
            v = make_float4(xv * ev.x, xv * ev.y, xv * ev.z, xv * ev.w);
        } else {
            v = *reinterpret_cast<const float4*>(&h[grow * 64 + c4 * 4]);
        }
        int base = lr * 129 + c4 * 4;
        sP[base + 0] = v.x; sP[base + 1] = v.y;
        sP[base + 2] = v.z; sP[base + 3] = v.w;
    }
    // A2: gather -> sP cols [64,128)
    {
        int wv = t >> 6, l = t & 63;
        int n = n0 + wv;
        int e0 = __builtin_amdgcn_readfirstlane(offs[n]);
        int e1 = __builtin_amdgcn_readfirstlane(offs[n + 1]);
        float4 a1 = make_float4(0.f, 0.f, 0.f, 0.f);
        float4 a2 = make_float4(0.f, 0.f, 0.f, 0.f);
        float4 a3 = make_float4(0.f, 0.f, 0.f, 0.f);
        float4 a4 = make_float4(0.f, 0.f, 0.f, 0.f);
        int e = e0;
        for (; e + 1 < e1; e += 2) {
            int p1 = elist[e], p2 = elist[e + 1];
            const float4* q1 = reinterpret_cast<const float4*>(M + (long)p1 * 512);
            const float4* q2 = reinterpret_cast<const float4*>(M + (long)p2 * 512);
            float4 v1 = q1[l], v2 = q1[64 + l];
            float4 v3 = q2[l], v4 = q2[64 + l];
            a1.x += v1.x; a1.y += v1.y; a1.z += v1.z; a1.w += v1.w;
            a2.x += v2.x; a2.y += v2.y; a2.z += v2.z; a2.w += v2.w;
            a3.x += v3.x; a3.y += v3.y; a3.z += v3.z; a3.w += v3.w;
            a4.x += v4.x; a4.y += v4.y; a4.z += v4.z; a4.w += v4.w;
        }
        if (e < e1) {
            int p = elist[e];
            const float4* q = reinterpret_cast<const float4*>(M + (long)p * 512);
            float4 v1 = q[l], v2 = q[64 + l];
            a1.x += v1.x; a1.y += v1.y; a1.z += v1.z; a1.w += v1.w;
            a2.x += v2.x; a2.y += v2.y; a2.z += v2.z; a2.w += v2.w;
        }
        a1.x += a3.x; a1.y += a3.y; a1.z += a3.z; a1.w += a3.w;
        a2.x += a4.x; a2.y += a4.y; a2.z += a4.z; a2.w += a4.w;
        int c4 = l & 15, br = l >> 4;
        int base1 = (wv * 8 + br) * 129 + 64 + c4 * 4;
        int base2 = (wv * 8 + 4 + br) * 129 + 64 + c4 * 4;
        sP[base1 + 0] = a1.x; sP[base1 + 1] = a1.y;
        sP[base1 + 2] = a1.z; sP[base1 + 3] = a1.w;
        sP[base2 + 0] = a2.x; sP[base2 + 1] = a2.y;
        sP[base2 + 2] = a2.z; sP[base2 + 3] = a2.w;
    }
    __syncthreads();

    int cg_ = t & 15, rg = t >> 4;    // rows 2rg, 2rg+1
    // B: update GEMM1 over k=0..128 (W1u broadcast from global/L1)
    float acc[2][4] = {};
    #pragma unroll 4
    for (int k = 0; k < 128; ++k) {
        float a0 = sP[(rg * 2 + 0) * 129 + k];
        float a1 = sP[(rg * 2 + 1) * 129 + k];
        float4 bb = *reinterpret_cast<const float4*>(&W1u[k * 64 + cg_ * 4]);
        acc[0][0] += a0 * bb.x; acc[0][1] += a0 * bb.y; acc[0][2] += a0 * bb.z; acc[0][3] += a0 * bb.w;
        acc[1][0] += a1 * bb.x; acc[1][1] += a1 * bb.y; acc[1][2] += a1 * bb.z; acc[1][3] += a1 * bb.w;
    }
    float4 bv1 = *reinterpret_cast<const float4*>(&b1u[cg_ * 4]);
    __syncthreads();
    #pragma unroll
    for (int i = 0; i < 2; ++i) {
        int base = (rg * 2 + i) * 129 + cg_ * 4;
        sP[base + 0] = elu_f(acc[i][0] + bv1.x);
        sP[base + 1] = elu_f(acc[i][1] + bv1.y);
        sP[base + 2] = elu_f(acc[i][2] + bv1.z);
        sP[base + 3] = elu_f(acc[i][3] + bv1.w);
    }
    __syncthreads();

    // C: update GEMM2 over k=0..64
    float acc2[2][4] = {};
    #pragma unroll 4
    for (int k = 0; k < 64; ++k) {
        float a0 = sP[(rg * 2 + 0) * 129 + k];
        float a1 = sP[(rg * 2 + 1) * 129 + k];
        float4 bb = *reinterpret_cast<const float4*>(&W2u[k * 64 + cg_ * 4]);
        acc2[0][0] += a0 * bb.x; acc2[0][1] += a0 * bb.y; acc2[0][2] += a0 * bb.z; acc2[0][3] += a0 * bb.w;
        acc2[1][0] += a1 * bb.x; acc2[1][1] += a1 * bb.y; acc2[1][2] += a1 * bb.z; acc2[1][3] += a1 * bb.w;
    }
    float4 bv2 = *reinterpret_cast<const float4*>(&b2u[cg_ * 4]);
    #pragma unroll
    for (int i = 0; i < 2; ++i) {
        int lr = rg * 2 + i;
        int nl = lr >> 3, b = lr & 7;
        float4 o = make_float4(acc2[i][0] + bv2.x, acc2[i][1] + bv2.y,
                               acc2[i][2] + bv2.z, acc2[i][3] + bv2.w);
        *reinterpret_cast<float4*>(
            &hout[((long)b * N + (n0 + nl)) * 64 + cg_ * 4]) = o;
        if (PREP) {  // stash into sP cols [64,128) (disjoint from GEMM2 reads)
            int base = lr * 129 + 64 + cg_ * 4;
            sP[base + 0] = o.x; sP[base + 1] = o.y;
            sP[base + 2] = o.z; sP[base + 3] = o.w;
        }
    }

    if (PREP) {
        __syncthreads();
        // D1: p1 = elu(rows @ W1p), reads sP cols [64,128), writes cols [0,64)
        float acc3[2][4] = {};
        #pragma unroll 4
        for (int k = 0; k < 64; ++k) {
            float a0 = sP[(rg * 2 + 0) * 129 + 64 + k];
            float a1 = sP[(rg * 2 + 1) * 129 + 64 + k];
            float4 bb = *reinterpret_cast<const float4*>(&W1p[k * 64 + cg_ * 4]);
            acc3[0][0] += a0 * bb.x; acc3[0][1] += a0 * bb.y; acc3[0][2] += a0 * bb.z; acc3[0][3] += a0 * bb.w;
            acc3[1][0] += a1 * bb.x; acc3[1][1] += a1 * bb.y; acc3[1][2] += a1 * bb.z; acc3[1][3] += a1 * bb.w;
        }
        #pragma unroll
        for (int i = 0; i < 2; ++i) {
            int base = (rg * 2 + i) * 129 + cg_ * 4;
            sP[base + 0] = elu_f(acc3[i][0]);
            sP[base + 1] = elu_f(acc3[i][1]);
            sP[base + 2] = elu_f(acc3[i][2]);
            sP[base + 3] = elu_f(acc3[i][3]);
        }
        __syncthreads();
        // D2: Mout = elu(p1 @ W2p), node-major
        float acc4[2][4] = {};
        #pragma unroll 4
        for (int k = 0; k < 64; ++k) {
            float a0 = sP[(rg * 2 + 0) * 129 + k];
            float a1 = sP[(rg * 2 + 1) * 129 + k];
            float4 bb = *reinterpret_cast<const float4*>(&W2p[k * 64 + cg_ * 4]);
            acc4[0][0] += a0 * bb.x; acc4[0][1] += a0 * bb.y; acc4[0][2] += a0 * bb.z; acc4[0][3] += a0 * bb.w;
            acc4[1][0] += a1 * bb.x; acc4[1][1] += a1 * bb.y; acc4[1][2] += a1 * bb.z; acc4[1][3] += a1 * bb.w;
        }
        #pragma unroll
        for (int i = 0; i < 2; ++i) {
            int lr = rg * 2 + i;
            int nl = lr >> 3, b = lr & 7;
            float4 o = make_float4(elu_f(acc4[i][0]), elu_f(acc4[i][1]),
                                   elu_f(acc4[i][2]), elu_f(acc4[i][3]));
            *reinterpret_cast<float4*>(
                &Mout[((long)(n0 + nl) * 8 + b) * 64 + cg_ * 4]) = o;
        }
    }
}

// ---------------- partial[yb,xb,:] = per-block head GEMV partial ----------------
// grid (XB,2); 8-slot LDS ring via global_load_lds, counted vmcnt(7).
__global__ __launch_bounds__(256) void k_head(const float* __restrict__ phi,   // [8][ND]
                                              const float* __restrict__ w0a,
                                              const float* __restrict__ w1a,
                                              float* __restrict__ part) {      // [2][XB][1024]
    __shared__ float smem[4 * 32 * 33];              // 16.9 KB; phi chunk + partials
    __shared__ __align__(16) float wb[8][1024];      // 32 KB ring (8 x 4KB)
    const float* wa = blockIdx.y ? w1a : w0a;
    int t = threadIdx.x;
    int k0 = blockIdx.x * KC;

    #pragma unroll
    for (int b = 0; b < 8; ++b)
        for (int kk = t; kk < KC; kk += 256)
            smem[b * KC + kk] = phi[(long)b * ND + k0 + kk];
    __syncthreads();

    int w = t >> 6, l = t & 63;
    int h4 = l & 31, kh = l >> 5;
    int kl = w * 2 + kh;                       // [0,8)
    const float* wp = wa + (long)(k0 + kl) * H + h4 * 4;

    float4 acc[8];
    #pragma unroll
    for (int b = 0; b < 8; ++b) acc[b] = make_float4(0.f, 0.f, 0.f, 0.f);

    unsigned my_off =
        (unsigned)(size_t)(__attribute__((address_space(3))) float*)&wb[0][0]
        + (unsigned)t * 16u;

    const float* wq = wp;
    #pragma unroll
    for (int j = 0; j < 8; ++j) {
        g2lds16(wq, &wb[j][w * 256]);
        wq += 8 * H;
    }

#define STEP(I, CNT, OFF, RE)                                              \
    {                                                                      \
        asm volatile("s_waitcnt vmcnt(" #CNT ")" ::: "memory");            \
        __builtin_amdgcn_sched_barrier(0);                                 \
        f32x4 w4;                                                          \
        asm volatile("ds_read_b128 %0, %1 offset:" #OFF                    \
                     : "=v"(w4) : "v"(my_off));                            \
        float pv[8];                                                       \
        _Pragma("unroll")                                                  \
        for (int b = 0; b < 8; ++b)                                        \
            pv[b] = smem[b * KC + (I) * 8 + kl];                           \
        asm volatile("s_waitcnt lgkmcnt(0)" ::: "memory");                 \
        __builtin_amdgcn_sched_barrier(0);                                 \
        _Pragma("unroll")                                                  \
        for (int b = 0; b < 8; ++b) {                                      \
            acc[b].x += pv[b] * w4.x; acc[b].y += pv[b] * w4.y;            \
            acc[b].z += pv[b] * w4.z; acc[b].w += pv[b] * w4.w;            \
        }                                                                  \
        if (RE) {                                                          \
            g2lds16(wq, &wb[(I) & 7][w * 256]);                            \
            wq += 8 * H;                                                   \
        }                                                                  \
    }

#define ROUND8(BASE, RE)                                                   \
    STEP(BASE + 0, 7, 0,     RE) STEP(BASE + 1, 7, 4096,  RE)              \
    STEP(BASE + 2, 7, 8192,  RE) STEP(BASE + 3, 7, 12288, RE)              \
    STEP(BASE + 4, 7, 16384, RE) STEP(BASE + 5, 7, 20480, RE)              \
    STEP(BASE + 6, 7, 24576, RE) STEP(BASE + 7, 7, 28672, RE)

    ROUND8(0, 1) ROUND8(8, 1) ROUND8(16, 1) ROUND8(24, 1)
    STEP(32, 7, 0,     0) STEP(33, 6, 4096,  0)
    STEP(34, 5, 8192,  0) STEP(35, 4, 12288, 0)
    STEP(36, 3, 16384, 0) STEP(37, 2, 20480, 0)
    STEP(38, 1, 24576, 0) STEP(39, 0, 28672, 0)
#undef ROUND8
#undef STEP

    #pragma unroll
    for (int b = 0; b < 8; ++b) {
        acc[b].x += __shfl_xor(acc[b].x, 32);
        acc[b].y += __shfl_xor(acc[b].y, 32);
        acc[b].z += __shfl_xor(acc[b].z, 32);
        acc[b].w += __shfl_xor(acc[b].w, 32);
    }
    __syncthreads();   // phi reads done; smem reused for partials
    if (kh == 0) {
        int base = (w * 32 + h4) * 33;
        #pragma unroll
        for (int b = 0; b < 8; ++b) {
            smem[base + b * 4 + 0] = acc[b].x;
            smem[base + b * 4 + 1] = acc[b].y;
            smem[base + b * 4 + 2] = acc[b].z;
            smem[base + b * 4 + 3] = acc[b].w;
        }
    }
    __syncthreads();

    int h4r = t & 31, br = t >> 5;
    float s0 = 0.f, s1 = 0.f, s2 = 0.f, s3 = 0.f;
    #pragma unroll
    for (int wv = 0; wv < 4; ++wv) {
        int idx = (wv * 32 + h4r) * 33 + br * 4;
        s0 += smem[idx + 0]; s1 += smem[idx + 1];
        s2 += smem[idx + 2]; s3 += smem[idx + 3];
    }
    float* pb = part + ((long)blockIdx.y * XB + blockIdx.x) * 1024;
    *reinterpret_cast<float4*>(&pb[br * H + h4r * 4]) =
        make_float4(s0, s1, s2, s3);
}

// ---------------- cooperative reduce + final ----------------
// grid 128 blocks: bx&15 = chunk c, bx>>4 selects 256 of 2048 outputs.
// Phase 1 writes hidden2[c][2048] (atomic-free); grid.sync; block 0 finals.
__global__ __launch_bounds__(256) void k_redfin(const float* __restrict__ part,
                                                float* __restrict__ hidden2,
                                                const float* __restrict__ b0a,
                                                const float* __restrict__ w0b,
                                                const float* __restrict__ b0b,
                                                const float* __restrict__ b1a,
                                                const float* __restrict__ w1b,
                                                const float* __restrict__ b1b,
                                                float* __restrict__ out) {
    cg::grid_group grid = cg::this_grid();
    {
        int bx = blockIdx.x;
        int c = bx & 15;
        int idx = (bx >> 4) * 256 + threadIdx.x;   // [0, 2048)
        int y = idx >> 10, j = idx & 1023;
        const float* p = part + (long)y * XB * 1024 + j;
        int x0 = (XB * c) >> 4, x1 = (XB * (c + 1)) >> 4;
        float s0 = 0.f, s1 = 0.f, s2 = 0.f, s3 = 0.f;
        int x = x0;
        for (; x + 3 < x1; x += 4) {
            s0 += p[(long)(x + 0) * 1024];
            s1 += p[(long)(x + 1) * 1024];
            s2 += p[(long)(x + 2) * 1024];
            s3 += p[(long)(x + 3) * 1024];
        }
        for (; x < x1; ++x) s0 += p[(long)x * 1024];
        hidden2[c * 2048 + idx] = s0 + s1 + s2 + s3;
    }
    grid.sync();
    if (blockIdx.x == 0 && threadIdx.x < 32) {
        int t = threadIdx.x;
        int head = t >> 4, b = (t >> 1) & 7, j = t & 1;
        int base = head * 1024 + b * H;
        const float* ba = head ? b1a : b0a;
        const float* wb2 = head ? w1b : w0b;
        const float* bb = head ? b1b : b0b;
        float acc = 0.0f;
        for (int hh = 0; hh < H; ++hh) {
            float hv = 0.0f;
            #pragma unroll
            for (int c = 0; c < 16; ++c) hv += hidden2[c * 2048 + base + hh];
            acc += elu_f(hv + ba[hh]) * wb2[hh * 2 + j];
        }
        out[b * 4 + head * 2 + j] = acc + bb[j];
    }
}

extern "C" void kernel_launch(void* const* d_in, const int* in_sizes, int n_in,
                              void* d_out, int out_size, void* d_ws, size_t ws_size,
                              hipStream_t stream) {
    const float* x      = (const float*)d_in[0];
    const int*   edges  = (const int*)d_in[1];
    const float* emb    = (const float*)d_in[2];
    const float* c1_pw1 = (const float*)d_in[3];
    const float* c1_pw2 = (const float*)d_in[4];
    const float* c1_uw1 = (const float*)d_in[5];
    const float* c1_ub1 = (const float*)d_in[6];
    const float* c1_uw2 = (const float*)d_in[7];
    const float* c1_ub2 = (const float*)d_in[8];
    const float* c2_pw1 = (const float*)d_in[9];
    const float* c2_pw2 = (const float*)d_in[10];
    const float* c2_uw1 = (const float*)d_in[11];
    const float* c2_ub1 = (const float*)d_in[12];
    const float* c2_uw2 = (const float*)d_in[13];
    const float* c2_ub2 = (const float*)d_in[14];
    const float* w0a    = (const float*)d_in[15];
    const float* b0a    = (const float*)d_in[16];
    const float* w0b    = (const float*)d_in[17];
    const float* b0b    = (const float*)d_in[18];
    const float* w1a    = (const float*)d_in[19];
    const float* b1a    = (const float*)d_in[20];
    const float* w1b    = (const float*)d_in[21];
    const float* b1b    = (const float*)d_in[22];
    float* out = (float*)d_out;

    float* hA      = (float*)d_ws;            // [BN, D] b-major (phi after conv2)
    float* hB      = hA + BND;                // [BN, D] b-major (conv1 out)
    float* Mu      = hB + BND;                // conv1 messages [N][8][64]; alias part
    float* M2      = Mu + BND;                // conv2 messages [N][8][64]
    float* hidden2 = M2 + BND;                // [16][2048] = 32768 floats
    int* cnt       = (int*)(hidden2 + 32768); // [N]
    int* cursor    = cnt + N;                 // [N] (contiguous after cnt)
    int* offs      = cursor + N;              // [N+1]
    int* elist     = offs + N + 1;            // [E]
    float* part    = Mu;                      // [2][XB][1024] = 2.048M <= BND

    // 1) CSR build: zero + count + scan + fill, one cooperative dispatch
    {
        void* args[] = {(void*)&edges, (void*)&cnt, (void*)&cursor,
                        (void*)&offs, (void*)&elist};
        hipLaunchCooperativeKernel((const void*)k_csr, dim3(256), dim3(256),
                                   args, 0, stream);
    }
    // 2) conv1 message prep (node-major Mu)
    k_prepare<<<(BN + 127) / 128, 512, 0, stream>>>(x, emb, c1_pw1, c1_pw2, Mu);
    // 3) conv1 gather+update (+ conv2 prepare); h computed inline from x,emb
    k_conv<1><<<N / 8, 512, 0, stream>>>(nullptr, x, emb, Mu, offs, elist,
                                         c1_uw1, c1_ub1, c1_uw2, c1_ub2, hB,
                                         c2_pw1, c2_pw2, M2);
    // 4) conv2 gather+update (writes hA = phi)
    k_conv<0><<<N / 8, 512, 0, stream>>>(hB, nullptr, nullptr, M2, offs, elist,
                                         c2_uw1, c2_ub1, c2_uw2, c2_ub2, hA,
                                         nullptr, nullptr, nullptr);
    // 5) heads
    k_head<<<dim3(XB, 2), 256, 0, stream>>>(hA, w0a, w1a, part);
    // 6) reduce + final, one cooperative dispatch
    {
        void* args[] = {(void*)&part, (void*)&hidden2,
                        (void*)&b0a, (void*)&w0b, (void*)&b0b,
                        (void*)&b1a, (void*)&w1b, (void*)&b1b, (void*)&out};
        hipLaunchCooperativeKernel((const void*)k_redfin, dim3(128), dim3(256),
                                   args, 0, stream);
    }
}

// Round 11
// 654.515 us; speedup vs baseline: 1.2174x; 1.2174x over previous
//
#include <hip/hip_runtime.h>

// GNN TARnet: h = x*emb -> 2x graph conv -> two prob heads.
// R14: revert of R13 (cooperative grid.sync measured at ~35us each on MI355X
//     -> k_csr 119us for ~15us of work; total 797). Restores the best-known
//     R12 structure exactly: 9 dispatches, non-cooperative, node-major M,
//     coalesced batch-contiguous gather, fused conv2-prepare, atomic-free
//     chunked reduce. Decision rule: if total lands 600-660 with k_head
//     (~116us, ~2.9TB/s pattern wall) the only >100us kernel, the structure
//     is at its practical floor.

constexpr int B = 8, N = 5000, E = 160000, D = 64, H = 128;
constexpr int BN = B * N;           // 40000
constexpr int ND = N * D;           // 320000
constexpr long BND = (long)BN * D;  // 2,560,000
constexpr int KC = 320;             // k-chunk per head block
constexpr int NIT = KC / 8;         // 40 k-iters per thread
constexpr int XB = ND / KC;         // 1000 x-blocks per head

using f32x4 = __attribute__((ext_vector_type(4))) float;

__device__ __forceinline__ float elu_f(float x) {
    return x > 0.0f ? x : __expf(x) - 1.0f;
}

__device__ __forceinline__ void g2lds16(const float* g, float* l) {
    __builtin_amdgcn_global_load_lds(
        (const __attribute__((address_space(1))) void*)g,
        (__attribute__((address_space(3))) void*)l, 16, 0, 0);
}

// ---------------- CSR scan + fill (count lives in k_prepare) ----------------
__global__ __launch_bounds__(256) void k_scan(const int* __restrict__ cnt,
                                              int* __restrict__ offs) {
    __shared__ int part[256];
    int t = threadIdx.x;
    const int CH = 20;
    int base = t * CH;
    int s = 0;
    for (int i = 0; i < CH; ++i) { int idx = base + i; if (idx < N) s += cnt[idx]; }
    part[t] = s;
    __syncthreads();
    for (int off = 1; off < 256; off <<= 1) {
        int add = (t >= off) ? part[t - off] : 0;
        __syncthreads();
        part[t] += add;
        __syncthreads();
    }
    int run = part[t] - s;
    for (int i = 0; i < CH; ++i) {
        int idx = base + i;
        if (idx < N) { offs[idx] = run; run += cnt[idx]; }
    }
    if (t == 255) offs[N] = run;
}

__global__ __launch_bounds__(256) void k_fill(const int* __restrict__ edges,
                                              const int* __restrict__ offs,
                                              int* __restrict__ cursor,
                                              int* __restrict__ elist) {
    int i = blockIdx.x * 256 + threadIdx.x;
    if (i < E) {
        int child = edges[2 * i + 1];
        int pos = offs[child] + atomicAdd(&cursor[child], 1);
        elist[pos] = edges[2 * i];
    }
}

// ---------------- prepare (conv1): M = elu(elu((x*emb) @ W1) @ W2) ----------
// Edge-count fused (grid 313x512 covers E); M written node-major
// M[(n*8+b)*64+c]; no hwt materialization.
__global__ __launch_bounds__(512) void k_prepare(const float* __restrict__ xsrc,
                                                 const float* __restrict__ emb,
                                                 const int* __restrict__ edges,
                                                 int* __restrict__ cnt,
                                                 const float* __restrict__ W1,
                                                 const float* __restrict__ W2,
                                                 float* __restrict__ M) {
    __shared__ float sW1[64 * 64];      // 16 KB
    __shared__ float sP[128 * 65];      // 33.3 KB
    int t = threadIdx.x;
    int r0 = blockIdx.x * 128;
    // fused edge count: one edge per thread across the grid
    {
        int i = blockIdx.x * 512 + t;
        if (i < E) atomicAdd(&cnt[edges[2 * i + 1]], 1);
    }
    for (int i = t; i < 4096; i += 512) sW1[i] = W1[i];
    for (int i = t; i < 128 * 64; i += 512) {
        int r = i >> 6, c = i & 63;
        int row = r0 + r;
        float v = 0.0f;
        if (row < BN) {
            int n = row % N;
            v = xsrc[row] * emb[n * 64 + c];
        }
        sP[r * 65 + c] = v;
    }
    __syncthreads();

    int cg = t & 15, rg = t >> 4;
    float acc[4][4] = {};
    #pragma unroll 4
    for (int k = 0; k < 64; ++k) {
        float a[4];
        #pragma unroll
        for (int i = 0; i < 4; ++i) a[i] = sP[(rg * 4 + i) * 65 + k];
        float4 bb = *reinterpret_cast<const float4*>(&sW1[k * 64 + cg * 4]);
        #pragma unroll
        for (int i = 0; i < 4; ++i) {
            acc[i][0] += a[i] * bb.x; acc[i][1] += a[i] * bb.y;
            acc[i][2] += a[i] * bb.z; acc[i][3] += a[i] * bb.w;
        }
    }
    __syncthreads();
    #pragma unroll
    for (int i = 0; i < 4; ++i)
        #pragma unroll
        for (int j = 0; j < 4; ++j)
            sP[(rg * 4 + i) * 65 + cg * 4 + j] = elu_f(acc[i][j]);
    __syncthreads();

    float acc2[4][4] = {};
    #pragma unroll 4
    for (int k = 0; k < 64; ++k) {
        float a[4];
        #pragma unroll
        for (int i = 0; i < 4; ++i) a[i] = sP[(rg * 4 + i) * 65 + k];
        float4 bb = *reinterpret_cast<const float4*>(&W2[k * 64 + cg * 4]);
        #pragma unroll
        for (int i = 0; i < 4; ++i) {
            acc2[i][0] += a[i] * bb.x; acc2[i][1] += a[i] * bb.y;
            acc2[i][2] += a[i] * bb.z; acc2[i][3] += a[i] * bb.w;
        }
    }
    #pragma unroll
    for (int i = 0; i < 4; ++i) {
        int row = r0 + rg * 4 + i;
        if (row < BN) {
            int b = row / N;
            int n = row - b * N;
            float4 o = make_float4(elu_f(acc2[i][0]), elu_f(acc2[i][1]),
                                   elu_f(acc2[i][2]), elu_f(acc2[i][3]));
            *reinterpret_cast<float4*>(&M[((long)n * 8 + b) * 64 + cg * 4]) = o;
        }
    }
}

// ---------------- fused conv: gather + update FFN (+ optional next-prepare) ----
// M node-major [N][8][64]; block = 8 nodes x 8 batches. PREP=1: h inline from
// x,emb; also runs conv2 prepare tail.
template <int PREP>
__global__ __launch_bounds__(512, 8) void k_conv(const float* __restrict__ h,
                                                 const float* __restrict__ xsrc,
                                                 const float* __restrict__ emb,
                                                 const float* __restrict__ M,
                                                 const int* __restrict__ offs,
                                                 const int* __restrict__ elist,
                                                 const float* __restrict__ W1u,  // [128][64]
                                                 const float* __restrict__ b1u,
                                                 const float* __restrict__ W2u,  // [64][64]
                                                 const float* __restrict__ b2u,
                                                 float* __restrict__ hout,
                                                 const float* __restrict__ W1p,  // [64][64]
                                                 const float* __restrict__ W2p,  // [64][64]
                                                 float* __restrict__ Mout) {
    __shared__ float sP[64 * 129];      // 33 KB; rows lr = n_local*8 + b
    int t = threadIdx.x;
    int n0 = blockIdx.x * 8;

    // A1: stage h rows -> sP cols [0,64): 1024 float4, 2 per thread
    #pragma unroll
    for (int q = 0; q < 2; ++q) {
        int s = t + q * 512;
        int lr = s >> 4, c4 = s & 15;
        int nl = lr >> 3, b = lr & 7;
        long grow = (long)b * N + (n0 + nl);
        float4 v;
        if (PREP) {
            float xv = xsrc[grow];
            float4 ev = *reinterpret_cast<const float4*>(
                &emb[(long)(n0 + nl) * 64 + c4 * 4]);
            v = make_float4(xv * ev.x, xv * ev.y, xv * ev.z, xv * ev.w);
        } else {
            v = *reinterpret_cast<const float4*>(&h[grow * 64 + c4 * 4]);
        }
        int base = lr * 129 + c4 * 4;
        sP[base + 0] = v.x; sP[base + 1] = v.y;
        sP[base + 2] = v.z; sP[base + 3] = v.w;
    }
    // A2: gather -> sP cols [64,128)
    {
        int wv = t >> 6, l = t & 63;
        int n = n0 + wv;
        int e0 = __builtin_amdgcn_readfirstlane(offs[n]);
        int e1 = __builtin_amdgcn_readfirstlane(offs[n + 1]);
        float4 a1 = make_float4(0.f, 0.f, 0.f, 0.f);
        float4 a2 = make_float4(0.f, 0.f, 0.f, 0.f);
        float4 a3 = make_float4(0.f, 0.f, 0.f, 0.f);
        float4 a4 = make_float4(0.f, 0.f, 0.f, 0.f);
        int e = e0;
        for (; e + 1 < e1; e += 2) {
            int p1 = elist[e], p2 = elist[e + 1];
            const float4* q1 = reinterpret_cast<const float4*>(M + (long)p1 * 512);
            const float4* q2 = reinterpret_cast<const float4*>(M + (long)p2 * 512);
            float4 v1 = q1[l], v2 = q1[64 + l];
            float4 v3 = q2[l], v4 = q2[64 + l];
            a1.x += v1.x; a1.y += v1.y; a1.z += v1.z; a1.w += v1.w;
            a2.x += v2.x; a2.y += v2.y; a2.z += v2.z; a2.w += v2.w;
            a3.x += v3.x; a3.y += v3.y; a3.z += v3.z; a3.w += v3.w;
            a4.x += v4.x; a4.y += v4.y; a4.z += v4.z; a4.w += v4.w;
        }
        if (e < e1) {
            int p = elist[e];
            const float4* q = reinterpret_cast<const float4*>(M + (long)p * 512);
            float4 v1 = q[l], v2 = q[64 + l];
            a1.x += v1.x; a1.y += v1.y; a1.z += v1.z; a1.w += v1.w;
            a2.x += v2.x; a2.y += v2.y; a2.z += v2.z; a2.w += v2.w;
        }
        a1.x += a3.x; a1.y += a3.y; a1.z += a3.z; a1.w += a3.w;
        a2.x += a4.x; a2.y += a4.y; a2.z += a4.z; a2.w += a4.w;
        int c4 = l & 15, br = l >> 4;
        int base1 = (wv * 8 + br) * 129 + 64 + c4 * 4;
        int base2 = (wv * 8 + 4 + br) * 129 + 64 + c4 * 4;
        sP[base1 + 0] = a1.x; sP[base1 + 1] = a1.y;
        sP[base1 + 2] = a1.z; sP[base1 + 3] = a1.w;
        sP[base2 + 0] = a2.x; sP[base2 + 1] = a2.y;
        sP[base2 + 2] = a2.z; sP[base2 + 3] = a2.w;
    }
    __syncthreads();

    int cg = t & 15, rg = t >> 4;    // rows 2rg, 2rg+1
    // B: update GEMM1 over k=0..128 (W1u broadcast from global/L1)
    float acc[2][4] = {};
    #pragma unroll 4
    for (int k = 0; k < 128; ++k) {
        float a0 = sP[(rg * 2 + 0) * 129 + k];
        float a1 = sP[(rg * 2 + 1) * 129 + k];
        float4 bb = *reinterpret_cast<const float4*>(&W1u[k * 64 + cg * 4]);
        acc[0][0] += a0 * bb.x; acc[0][1] += a0 * bb.y; acc[0][2] += a0 * bb.z; acc[0][3] += a0 * bb.w;
        acc[1][0] += a1 * bb.x; acc[1][1] += a1 * bb.y; acc[1][2] += a1 * bb.z; acc[1][3] += a1 * bb.w;
    }
    float4 bv1 = *reinterpret_cast<const float4*>(&b1u[cg * 4]);
    __syncthreads();
    #pragma unroll
    for (int i = 0; i < 2; ++i) {
        int base = (rg * 2 + i) * 129 + cg * 4;
        sP[base + 0] = elu_f(acc[i][0] + bv1.x);
        sP[base + 1] = elu_f(acc[i][1] + bv1.y);
        sP[base + 2] = elu_f(acc[i][2] + bv1.z);
        sP[base + 3] = elu_f(acc[i][3] + bv1.w);
    }
    __syncthreads();

    // C: update GEMM2 over k=0..64
    float acc2[2][4] = {};
    #pragma unroll 4
    for (int k = 0; k < 64; ++k) {
        float a0 = sP[(rg * 2 + 0) * 129 + k];
        float a1 = sP[(rg * 2 + 1) * 129 + k];
        float4 bb = *reinterpret_cast<const float4*>(&W2u[k * 64 + cg * 4]);
        acc2[0][0] += a0 * bb.x; acc2[0][1] += a0 * bb.y; acc2[0][2] += a0 * bb.z; acc2[0][3] += a0 * bb.w;
        acc2[1][0] += a1 * bb.x; acc2[1][1] += a1 * bb.y; acc2[1][2] += a1 * bb.z; acc2[1][3] += a1 * bb.w;
    }
    float4 bv2 = *reinterpret_cast<const float4*>(&b2u[cg * 4]);
    #pragma unroll
    for (int i = 0; i < 2; ++i) {
        int lr = rg * 2 + i;
        int nl = lr >> 3, b = lr & 7;
        float4 o = make_float4(acc2[i][0] + bv2.x, acc2[i][1] + bv2.y,
                               acc2[i][2] + bv2.z, acc2[i][3] + bv2.w);
        *reinterpret_cast<float4*>(
            &hout[((long)b * N + (n0 + nl)) * 64 + cg * 4]) = o;
        if (PREP) {  // stash into sP cols [64,128) (disjoint from GEMM2 reads)
            int base = lr * 129 + 64 + cg * 4;
            sP[base + 0] = o.x; sP[base + 1] = o.y;
            sP[base + 2] = o.z; sP[base + 3] = o.w;
        }
    }

    if (PREP) {
        __syncthreads();
        // D1: p1 = elu(rows @ W1p), reads sP cols [64,128), writes cols [0,64)
        float acc3[2][4] = {};
        #pragma unroll 4
        for (int k = 0; k < 64; ++k) {
            float a0 = sP[(rg * 2 + 0) * 129 + 64 + k];
            float a1 = sP[(rg * 2 + 1) * 129 + 64 + k];
            float4 bb = *reinterpret_cast<const float4*>(&W1p[k * 64 + cg * 4]);
            acc3[0][0] += a0 * bb.x; acc3[0][1] += a0 * bb.y; acc3[0][2] += a0 * bb.z; acc3[0][3] += a0 * bb.w;
            acc3[1][0] += a1 * bb.x; acc3[1][1] += a1 * bb.y; acc3[1][2] += a1 * bb.z; acc3[1][3] += a1 * bb.w;
        }
        #pragma unroll
        for (int i = 0; i < 2; ++i) {
            int base = (rg * 2 + i) * 129 + cg * 4;
            sP[base + 0] = elu_f(acc3[i][0]);
            sP[base + 1] = elu_f(acc3[i][1]);
            sP[base + 2] = elu_f(acc3[i][2]);
            sP[base + 3] = elu_f(acc3[i][3]);
        }
        __syncthreads();
        // D2: Mout = elu(p1 @ W2p), node-major
        float acc4[2][4] = {};
        #pragma unroll 4
        for (int k = 0; k < 64; ++k) {
            float a0 = sP[(rg * 2 + 0) * 129 + k];
            float a1 = sP[(rg * 2 + 1) * 129 + k];
            float4 bb = *reinterpret_cast<const float4*>(&W2p[k * 64 + cg * 4]);
            acc4[0][0] += a0 * bb.x; acc4[0][1] += a0 * bb.y; acc4[0][2] += a0 * bb.z; acc4[0][3] += a0 * bb.w;
            acc4[1][0] += a1 * bb.x; acc4[1][1] += a1 * bb.y; acc4[1][2] += a1 * bb.z; acc4[1][3] += a1 * bb.w;
        }
        #pragma unroll
        for (int i = 0; i < 2; ++i) {
            int lr = rg * 2 + i;
            int nl = lr >> 3, b = lr & 7;
            float4 o = make_float4(elu_f(acc4[i][0]), elu_f(acc4[i][1]),
                                   elu_f(acc4[i][2]), elu_f(acc4[i][3]));
            *reinterpret_cast<float4*>(
                &Mout[((long)(n0 + nl) * 8 + b) * 64 + cg * 4]) = o;
        }
    }
}

// ---------------- partial[yb,xb,:] = per-block head GEMV partial ----------------
// grid (XB,2); 8-slot LDS ring via global_load_lds, counted vmcnt(7).
__global__ __launch_bounds__(256) void k_head(const float* __restrict__ phi,   // [8][ND]
                                              const float* __restrict__ w0a,
                                              const float* __restrict__ w1a,
                                              float* __restrict__ part) {      // [2][XB][1024]
    __shared__ float smem[4 * 32 * 33];              // 16.9 KB; phi chunk + partials
    __shared__ __align__(16) float wb[8][1024];      // 32 KB ring (8 x 4KB)
    const float* wa = blockIdx.y ? w1a : w0a;
    int t = threadIdx.x;
    int k0 = blockIdx.x * KC;

    #pragma unroll
    for (int b = 0; b < 8; ++b)
        for (int kk = t; kk < KC; kk += 256)
            smem[b * KC + kk] = phi[(long)b * ND + k0 + kk];
    __syncthreads();

    int w = t >> 6, l = t & 63;
    int h4 = l & 31, kh = l >> 5;
    int kl = w * 2 + kh;                       // [0,8)
    const float* wp = wa + (long)(k0 + kl) * H + h4 * 4;

    float4 acc[8];
    #pragma unroll
    for (int b = 0; b < 8; ++b) acc[b] = make_float4(0.f, 0.f, 0.f, 0.f);

    unsigned my_off =
        (unsigned)(size_t)(__attribute__((address_space(3))) float*)&wb[0][0]
        + (unsigned)t * 16u;

    const float* wq = wp;
    #pragma unroll
    for (int j = 0; j < 8; ++j) {
        g2lds16(wq, &wb[j][w * 256]);
        wq += 8 * H;
    }

#define STEP(I, CNT, OFF, RE)                                              \
    {                                                                      \
        asm volatile("s_waitcnt vmcnt(" #CNT ")" ::: "memory");            \
        __builtin_amdgcn_sched_barrier(0);                                 \
        f32x4 w4;                                                          \
        asm volatile("ds_read_b128 %0, %1 offset:" #OFF                    \
                     : "=v"(w4) : "v"(my_off));                            \
        float pv[8];                                                       \
        _Pragma("unroll")                                                  \
        for (int b = 0; b < 8; ++b)                                        \
            pv[b] = smem[b * KC + (I) * 8 + kl];                           \
        asm volatile("s_waitcnt lgkmcnt(0)" ::: "memory");                 \
        __builtin_amdgcn_sched_barrier(0);                                 \
        _Pragma("unroll")                                                  \
        for (int b = 0; b < 8; ++b) {                                      \
            acc[b].x += pv[b] * w4.x; acc[b].y += pv[b] * w4.y;            \
            acc[b].z += pv[b] * w4.z; acc[b].w += pv[b] * w4.w;            \
        }                                                                  \
        if (RE) {                                                          \
            g2lds16(wq, &wb[(I) & 7][w * 256]);                            \
            wq += 8 * H;                                                   \
        }                                                                  \
    }

#define ROUND8(BASE, RE)                                                   \
    STEP(BASE + 0, 7, 0,     RE) STEP(BASE + 1, 7, 4096,  RE)              \
    STEP(BASE + 2, 7, 8192,  RE) STEP(BASE + 3, 7, 12288, RE)              \
    STEP(BASE + 4, 7, 16384, RE) STEP(BASE + 5, 7, 20480, RE)              \
    STEP(BASE + 6, 7, 24576, RE) STEP(BASE + 7, 7, 28672, RE)

    ROUND8(0, 1) ROUND8(8, 1) ROUND8(16, 1) ROUND8(24, 1)
    STEP(32, 7, 0,     0) STEP(33, 6, 4096,  0)
    STEP(34, 5, 8192,  0) STEP(35, 4, 12288, 0)
    STEP(36, 3, 16384, 0) STEP(37, 2, 20480, 0)
    STEP(38, 1, 24576, 0) STEP(39, 0, 28672, 0)
#undef ROUND8
#undef STEP

    #pragma unroll
    for (int b = 0; b < 8; ++b) {
        acc[b].x += __shfl_xor(acc[b].x, 32);
        acc[b].y += __shfl_xor(acc[b].y, 32);
        acc[b].z += __shfl_xor(acc[b].z, 32);
        acc[b].w += __shfl_xor(acc[b].w, 32);
    }
    __syncthreads();   // phi reads done; smem reused for partials
    if (kh == 0) {
        int base = (w * 32 + h4) * 33;
        #pragma unroll
        for (int b = 0; b < 8; ++b) {
            smem[base + b * 4 + 0] = acc[b].x;
            smem[base + b * 4 + 1] = acc[b].y;
            smem[base + b * 4 + 2] = acc[b].z;
            smem[base + b * 4 + 3] = acc[b].w;
        }
    }
    __syncthreads();

    int h4r = t & 31, br = t >> 5;
    float s0 = 0.f, s1 = 0.f, s2 = 0.f, s3 = 0.f;
    #pragma unroll
    for (int wv = 0; wv < 4; ++wv) {
        int idx = (wv * 32 + h4r) * 33 + br * 4;
        s0 += smem[idx + 0]; s1 += smem[idx + 1];
        s2 += smem[idx + 2]; s3 += smem[idx + 3];
    }
    float* pb = part + ((long)blockIdx.y * XB + blockIdx.x) * 1024;
    *reinterpret_cast<float4*>(&pb[br * H + h4r * 4]) =
        make_float4(s0, s1, s2, s3);
}

// ---------------- hidden2[c][y*1024+j] = sum_{x in chunk c} part[y,x,j] --------
// Atomic-free: each (c, output) pair owned by exactly one thread.
__global__ __launch_bounds__(256) void k_reduce(const float* __restrict__ part,
                                                float* __restrict__ hidden2) {
    int idx = blockIdx.x * 256 + threadIdx.x;      // [0, 2048)
    int c = blockIdx.y;                            // [0, 16)
    int y = idx >> 10, j = idx & 1023;
    const float* p = part + (long)y * XB * 1024 + j;
    int x0 = (XB * c) >> 4, x1 = (XB * (c + 1)) >> 4;
    float s0 = 0.f, s1 = 0.f, s2 = 0.f, s3 = 0.f;
    int x = x0;
    for (; x + 3 < x1; x += 4) {
        s0 += p[(long)(x + 0) * 1024];
        s1 += p[(long)(x + 1) * 1024];
        s2 += p[(long)(x + 2) * 1024];
        s3 += p[(long)(x + 3) * 1024];
    }
    for (; x < x1; ++x) s0 += p[(long)x * 1024];
    hidden2[c * 2048 + idx] = s0 + s1 + s2 + s3;
}

// ---------------- out[b, head*2+j] = elu(sum_c hidden2 + ba) @ wb + bb ---------
__global__ __launch_bounds__(64) void k_final(const float* __restrict__ hidden2,
                                              const float* __restrict__ b0a,
                                              const float* __restrict__ w0b,
                                              const float* __restrict__ b0b,
                                              const float* __restrict__ b1a,
                                              const float* __restrict__ w1b,
                                              const float* __restrict__ b1b,
                                              float* __restrict__ out) {
    int t = threadIdx.x;
    if (t >= 32) return;
    int head = t >> 4, b = (t >> 1) & 7, j = t & 1;
    int base = head * 1024 + b * H;
    const float* ba = head ? b1a : b0a;
    const float* wb = head ? w1b : w0b;
    const float* bb = head ? b1b : b0b;
    float acc = 0.0f;
    for (int hh = 0; hh < H; ++hh) {
        float hv = 0.0f;
        #pragma unroll
        for (int c = 0; c < 16; ++c) hv += hidden2[c * 2048 + base + hh];
        acc += elu_f(hv + ba[hh]) * wb[hh * 2 + j];
    }
    out[b * 4 + head * 2 + j] = acc + bb[j];
}

extern "C" void kernel_launch(void* const* d_in, const int* in_sizes, int n_in,
                              void* d_out, int out_size, void* d_ws, size_t ws_size,
                              hipStream_t stream) {
    const float* x      = (const float*)d_in[0];
    const int*   edges  = (const int*)d_in[1];
    const float* emb    = (const float*)d_in[2];
    const float* c1_pw1 = (const float*)d_in[3];
    const float* c1_pw2 = (const float*)d_in[4];
    const float* c1_uw1 = (const float*)d_in[5];
    const float* c1_ub1 = (const float*)d_in[6];
    const float* c1_uw2 = (const float*)d_in[7];
    const float* c1_ub2 = (const float*)d_in[8];
    const float* c2_pw1 = (const float*)d_in[9];
    const float* c2_pw2 = (const float*)d_in[10];
    const float* c2_uw1 = (const float*)d_in[11];
    const float* c2_ub1 = (const float*)d_in[12];
    const float* c2_uw2 = (const float*)d_in[13];
    const float* c2_ub2 = (const float*)d_in[14];
    const float* w0a    = (const float*)d_in[15];
    const float* b0a    = (const float*)d_in[16];
    const float* w0b    = (const float*)d_in[17];
    const float* b0b    = (const float*)d_in[18];
    const float* w1a    = (const float*)d_in[19];
    const float* b1a    = (const float*)d_in[20];
    const float* w1b    = (const float*)d_in[21];
    const float* b1b    = (const float*)d_in[22];
    float* out = (float*)d_out;

    float* hA      = (float*)d_ws;           // [BN, D] b-major (phi after conv2)
    float* hB      = hA + BND;               // [BN, D] b-major (conv1 out)
    float* Mu      = hB + BND;               // conv1 messages [N][8][64]; alias part
    float* M2      = Mu + BND;               // conv2 messages [N][8][64]
    float* hidden2 = M2 + BND;               // [16][2048] = 32768 floats
    int* cnt       = (int*)(hidden2 + 32768); // [N]
    int* cursor    = cnt + N;                // [N] (contiguous after cnt)
    int* offs      = cursor + N;             // [N+1]
    int* elist     = offs + N + 1;           // [E]
    float* part    = Mu;                     // [2][XB][1024] = 2.048M <= BND

    // 1) zero cnt+cursor (contiguous)
    hipMemsetAsync(cnt, 0, 2 * N * sizeof(int), stream);
    // 2) conv1 message prep (+ fused edge count)
    k_prepare<<<(BN + 127) / 128, 512, 0, stream>>>(x, emb, edges, cnt,
                                                    c1_pw1, c1_pw2, Mu);
    // 3) CSR scan, 4) CSR fill
    k_scan<<<1, 256, 0, stream>>>(cnt, offs);
    k_fill<<<(E + 255) / 256, 256, 0, stream>>>(edges, offs, cursor, elist);
    // 5) conv1 gather+update (+ conv2 prepare); h computed inline from x,emb
    k_conv<1><<<N / 8, 512, 0, stream>>>(nullptr, x, emb, Mu, offs, elist,
                                         c1_uw1, c1_ub1, c1_uw2, c1_ub2, hB,
                                         c2_pw1, c2_pw2, M2);
    // 6) conv2 gather+update (writes hA = phi)
    k_conv<0><<<N / 8, 512, 0, stream>>>(hB, nullptr, nullptr, M2, offs, elist,
                                         c2_uw1, c2_ub1, c2_uw2, c2_ub2, hA,
                                         nullptr, nullptr, nullptr);
    // 7) heads, 8) chunked reduce (atomic-free), 9) final
    k_head<<<dim3(XB, 2), 256, 0, stream>>>(hA, w0a, w1a, part);
    k_reduce<<<dim3(8, 16), 256, 0, stream>>>(part, hidden2);
    k_final<<<1, 64, 0, stream>>>(hidden2, b0a, w0b, b0b, b1a, w1b, b1b, out);
}